// Round 12
// baseline (178.383 us; speedup 1.0000x reference)
//
#include <hip/hip_runtime.h>

// Fused 6-layer MLP, v13: coalesced stage -> transposed bf16 x in LDS,
// W1 f32 via SGPR (wave-uniform k-slice), conflict-free b32 x reads.
// Grid 2048 x 512 thr (8 waves; 2 blocks/CU at 64.2 KB LDS). Block = 32 rows.
//   Stage: wave w stages rows {w, w+8, w+16, w+24}: 1KB-contiguous float4
//     bursts, cvt_pk -> bf16 k-pairs, ds_write_b32 to xT[p*33 + r]
//     (banks 2l+r: 2-way = free).
//   Compute: wave w owns pairs p in [49w, 49w+49) (8x49=392=784/2 exact).
//     Per iter: 1 ds_read_b32 (banks p+r: conflict-free), W1 rows 2p,2p+1
//     via s_load (wave-uniform, f32, full precision), 24 FMA + 1 shl.
//     Lanes 32-63 duplicate rows (broadcast reads, skip partial write).
//   Reduce: partials [32 rows][8 waves][12] in LDS (stride 97, ~2-way);
//     epilogue on 256 threads: 8 slots/row, shfl_xor(1,2,4), tiny layers
//     redundant per slot, 19 stores split 8 ways.

__device__ __forceinline__ float ftanh(float v) {
    float e = __expf(2.0f * v);
    return 1.0f - 2.0f / (e + 1.0f);
}

__device__ __forceinline__ uint32_t cvtpk(float lo, float hi) {
    uint32_t d;
    asm("v_cvt_pk_bf16_f32 %0, %1, %2" : "=v"(d) : "v"(lo), "v"(hi));
    return d;
}

__global__ __launch_bounds__(512, 4)
void mlp_fused13(const float* __restrict__ x,
                 const float* __restrict__ W1, const float* __restrict__ b1,
                 const float* __restrict__ W2, const float* __restrict__ b2,
                 const float* __restrict__ W3, const float* __restrict__ b3,
                 const float* __restrict__ W4, const float* __restrict__ b4,
                 const float* __restrict__ W5, const float* __restrict__ b5,
                 const float* __restrict__ W6, const float* __restrict__ b6,
                 float* __restrict__ out)
{
    __shared__ uint32_t xT[392 * 33];   // [pair p][row r], 51,744 B
    __shared__ float    pt[32 * 97];    // [row r][slot w*12+j], 12,416 B

    const int tid  = threadIdx.x;
    const int wave = tid >> 6;          // 0..7
    const int lane = tid & 63;
    const size_t row0 = (size_t)blockIdx.x << 5;    // 32 rows per block

    // ---- stage: 4 rows per wave, coalesced 1KB bursts, transposed bf16 ----
#pragma unroll
    for (int i = 0; i < 4; ++i) {
        const int r = 8 * i + wave;
        const float* xp = x + (row0 + r) * 784;
#pragma unroll
        for (int j = 0; j < 3; ++j) {
            float4 v = *(const float4*)(xp + 256 * j + 4 * lane);
            uint32_t q0 = cvtpk(v.x, v.y);
            uint32_t q1 = cvtpk(v.z, v.w);
            const int p0 = 128 * j + 2 * lane;
            xT[p0 * 33 + r]       = q0;
            xT[(p0 + 1) * 33 + r] = q1;
        }
        if (lane < 4) {                 // cols 768..783 -> pairs 384..391
            float4 v = *(const float4*)(xp + 768 + 4 * lane);
            uint32_t q0 = cvtpk(v.x, v.y);
            uint32_t q1 = cvtpk(v.z, v.w);
            const int p0 = 384 + 2 * lane;
            xT[p0 * 33 + r]       = q0;
            xT[(p0 + 1) * 33 + r] = q1;
        }
    }
    __syncthreads();

    // ---- compute: wave-uniform k-slice, W1 from SGPRs ----
    {
        const int r = lane & 31;
        float acc[12];
#pragma unroll
        for (int j = 0; j < 12; ++j) acc[j] = 0.f;

        const int pbase = 49 * wave;
#pragma unroll 7
        for (int t = 0; t < 49; ++t) {
            const int p = pbase + t;
            uint32_t ux = xT[p * 33 + r];
            float xlo = __uint_as_float(ux << 16);
            float xhi = __uint_as_float(ux & 0xffff0000u);
            const float* wk = W1 + (size_t)p * 24;   // rows 2p, 2p+1 (uniform -> s_load)
#pragma unroll
            for (int j = 0; j < 12; ++j) acc[j] += xlo * wk[j];
#pragma unroll
            for (int j = 0; j < 12; ++j) acc[j] += xhi * wk[12 + j];
        }
        if (lane < 32) {
#pragma unroll
            for (int j = 0; j < 12; ++j) pt[r * 97 + wave * 12 + j] = acc[j];
        }
    }
    __syncthreads();

    // ---- epilogue: 256 threads, 8 slots per row ----
    if (tid < 256) {
        const int r  = tid >> 3;
        const int s8 = tid & 7;
        const int row = (int)row0 + r;

        float h1[12];
#pragma unroll
        for (int j = 0; j < 12; ++j) {
            float z = pt[r * 97 + s8 * 12 + j];
            z += __shfl_xor(z, 1);
            z += __shfl_xor(z, 2);
            z += __shfl_xor(z, 4);
            h1[j] = ftanh(z + b1[j]);
        }

        float h2[10];
#pragma unroll
        for (int m = 0; m < 10; ++m) {
            float s = b2[m];
#pragma unroll
            for (int j = 0; j < 12; ++j) s += h1[j] * W2[j * 10 + m];
            h2[m] = ftanh(s);
        }
        float h3[8];
#pragma unroll
        for (int m = 0; m < 8; ++m) {
            float s = b3[m];
#pragma unroll
            for (int j = 0; j < 10; ++j) s += h2[j] * W3[j * 8 + m];
            h3[m] = ftanh(s);
        }
        float h4[6];
#pragma unroll
        for (int m = 0; m < 6; ++m) {
            float s = b4[m];
#pragma unroll
            for (int j = 0; j < 8; ++j) s += h3[j] * W4[j * 6 + m];
            h4[m] = ftanh(s);
        }
        float h5[4];
#pragma unroll
        for (int m = 0; m < 4; ++m) {
            float s = b5[m];
#pragma unroll
            for (int j = 0; j < 6; ++j) s += h4[j] * W5[j * 4 + m];
            h5[m] = ftanh(s);
        }
        float o[10];
#pragma unroll
        for (int m = 0; m < 10; ++m) {
            float s = b6[m];
#pragma unroll
            for (int j = 0; j < 4; ++j) s += h5[j] * W6[j * 10 + m];
            o[m] = s;   // logits
        }

        const size_t H1o = 655360, H2o = 1441792, H3o = 2097152, H4o = 2621440, H5o = 3014656;
        float2* po  = (float2*)(out +       (size_t)row * 10);
        float4* ph1 = (float4*)(out + H1o + (size_t)row * 12);
        float2* ph2 = (float2*)(out + H2o + (size_t)row * 10);
        float4* ph3 = (float4*)(out + H3o + (size_t)row * 8);
        float2* ph4 = (float2*)(out + H4o + (size_t)row * 6);
        float4* ph5 = (float4*)(out + H5o + (size_t)row * 4);

        switch (s8) {
            case 0:
                po[0] = make_float2(o[0], o[1]);
                po[1] = make_float2(o[2], o[3]);
                po[2] = make_float2(o[4], o[5]);
                break;
            case 1:
                po[3] = make_float2(o[6], o[7]);
                po[4] = make_float2(o[8], o[9]);
                ph4[0] = make_float2(h4[0], h4[1]);
                break;
            case 2:
                ph1[0] = make_float4(h1[0], h1[1], h1[2], h1[3]);
                ph1[1] = make_float4(h1[4], h1[5], h1[6], h1[7]);
                ph4[1] = make_float2(h4[2], h4[3]);
                break;
            case 3:
                ph1[2] = make_float4(h1[8], h1[9], h1[10], h1[11]);
                ph2[0] = make_float2(h2[0], h2[1]);
                ph4[2] = make_float2(h4[4], h4[5]);
                break;
            case 4:
                ph2[1] = make_float2(h2[2], h2[3]);
                ph2[2] = make_float2(h2[4], h2[5]);
                break;
            case 5:
                ph2[3] = make_float2(h2[6], h2[7]);
                ph2[4] = make_float2(h2[8], h2[9]);
                break;
            case 6:
                ph3[0] = make_float4(h3[0], h3[1], h3[2], h3[3]);
                ph5[0] = make_float4(h5[0], h5[1], h5[2], h5[3]);
                break;
            default:
                ph3[1] = make_float4(h3[4], h3[5], h3[6], h3[7]);
                break;
        }
    }
}

extern "C" void kernel_launch(void* const* d_in, const int* in_sizes, int n_in,
                              void* d_out, int out_size, void* d_ws, size_t ws_size,
                              hipStream_t stream) {
    (void)in_sizes; (void)n_in; (void)d_ws; (void)ws_size; (void)out_size;
    mlp_fused13<<<2048, 512, 0, stream>>>(
        (const float*)d_in[0],
        (const float*)d_in[1],  (const float*)d_in[2],
        (const float*)d_in[3],  (const float*)d_in[4],
        (const float*)d_in[5],  (const float*)d_in[6],
        (const float*)d_in[7],  (const float*)d_in[8],
        (const float*)d_in[9],  (const float*)d_in[10],
        (const float*)d_in[11], (const float*)d_in[12],
        (float*)d_out);
}

// Round 13
// 119.721 us; speedup vs baseline: 1.4900x; 1.4900x over previous
//
#include <hip/hip_runtime.h>

// Fused 6-layer MLP, v14: v13 + readfirstlane-forced wave (the fix).
// Coalesced stage -> transposed bf16 x in LDS; W1 f32 via s_load (wave-uniform
// SGPR address); conflict-free ds_read_b32 x reads.
// Grid 2048 x 512 thr (8 waves; 2 blocks/CU at 64.2 KB LDS). Block = 32 rows.
//   Stage: wave w stages rows {w, w+8, w+16, w+24}: 1KB-contiguous float4
//     bursts, cvt_pk -> bf16 k-pairs, ds_write_b32 to xT[p*33 + r]
//     (banks 2l+r: 2-way = free).
//   Compute: wave w owns pairs p in [49w, 49w+49) (8x49=392 exact).
//     Per iter: 1 ds_read_b32 (banks p+r: conflict-free), W1 rows 2p,2p+1
//     from SGPRs (s_load, full f32), 24 FMA + 2 bit-ops.
//     Lanes 32-63 duplicate rows 0..31 (broadcast reads, skip partial write).
//   Reduce: partials [32 rows][8 waves][12] in LDS stride 97; epilogue on
//     256 threads: 8 slots/row, shfl_xor(1,2,4), tiny layers redundant,
//     19 stores split 8 ways.

__device__ __forceinline__ float ftanh(float v) {
    float e = __expf(2.0f * v);
    return 1.0f - 2.0f / (e + 1.0f);
}

__device__ __forceinline__ uint32_t cvtpk(float lo, float hi) {
    uint32_t d;
    asm("v_cvt_pk_bf16_f32 %0, %1, %2" : "=v"(d) : "v"(lo), "v"(hi));
    return d;
}

__global__ __launch_bounds__(512, 4)
void mlp_fused14(const float* __restrict__ x,
                 const float* __restrict__ W1, const float* __restrict__ b1,
                 const float* __restrict__ W2, const float* __restrict__ b2,
                 const float* __restrict__ W3, const float* __restrict__ b3,
                 const float* __restrict__ W4, const float* __restrict__ b4,
                 const float* __restrict__ W5, const float* __restrict__ b5,
                 const float* __restrict__ W6, const float* __restrict__ b6,
                 float* __restrict__ out)
{
    __shared__ uint32_t xT[392 * 33];   // [pair p][row r], 51,744 B
    __shared__ float    pt[32 * 97];    // [row r][slot w*12+j], 12,416 B

    const int tid  = threadIdx.x;
    const int wave = __builtin_amdgcn_readfirstlane(tid >> 6);   // SGPR! (the fix)
    const int lane = tid & 63;
    const size_t row0 = (size_t)blockIdx.x << 5;    // 32 rows per block

    // ---- stage: 4 rows per wave, coalesced 1KB bursts, transposed bf16 ----
#pragma unroll
    for (int i = 0; i < 4; ++i) {
        const int r = 8 * i + wave;
        const float* xp = x + (row0 + r) * 784;
#pragma unroll
        for (int j = 0; j < 3; ++j) {
            float4 v = *(const float4*)(xp + 256 * j + 4 * lane);
            uint32_t q0 = cvtpk(v.x, v.y);
            uint32_t q1 = cvtpk(v.z, v.w);
            const int p0 = 128 * j + 2 * lane;
            xT[p0 * 33 + r]       = q0;
            xT[(p0 + 1) * 33 + r] = q1;
        }
        if (lane < 4) {                 // cols 768..783 -> pairs 384..391
            float4 v = *(const float4*)(xp + 768 + 4 * lane);
            uint32_t q0 = cvtpk(v.x, v.y);
            uint32_t q1 = cvtpk(v.z, v.w);
            const int p0 = 384 + 2 * lane;
            xT[p0 * 33 + r]       = q0;
            xT[(p0 + 1) * 33 + r] = q1;
        }
    }
    __syncthreads();

    // ---- compute: wave-uniform k-slice, W1 f32 from SGPRs ----
    {
        const int r = lane & 31;
        float acc[12];
#pragma unroll
        for (int j = 0; j < 12; ++j) acc[j] = 0.f;

        const int pbase = 49 * wave;    // scalar (wave is SGPR)
#pragma unroll 7
        for (int t = 0; t < 49; ++t) {
            const int p = pbase + t;
            uint32_t ux = xT[p * 33 + r];
            float xlo = __uint_as_float(ux << 16);
            float xhi = __uint_as_float(ux & 0xffff0000u);
            const float* wk = W1 + (size_t)p * 24;   // scalar addr -> s_load
#pragma unroll
            for (int j = 0; j < 12; ++j) acc[j] += xlo * wk[j];
#pragma unroll
            for (int j = 0; j < 12; ++j) acc[j] += xhi * wk[12 + j];
        }
        if (lane < 32) {
#pragma unroll
            for (int j = 0; j < 12; ++j) pt[r * 97 + wave * 12 + j] = acc[j];
        }
    }
    __syncthreads();

    // ---- epilogue: 256 threads, 8 slots per row ----
    if (tid < 256) {
        const int r  = tid >> 3;
        const int s8 = tid & 7;
        const int row = (int)row0 + r;

        float h1[12];
#pragma unroll
        for (int j = 0; j < 12; ++j) {
            float z = pt[r * 97 + s8 * 12 + j];
            z += __shfl_xor(z, 1);
            z += __shfl_xor(z, 2);
            z += __shfl_xor(z, 4);
            h1[j] = ftanh(z + b1[j]);
        }

        float h2[10];
#pragma unroll
        for (int m = 0; m < 10; ++m) {
            float s = b2[m];
#pragma unroll
            for (int j = 0; j < 12; ++j) s += h1[j] * W2[j * 10 + m];
            h2[m] = ftanh(s);
        }
        float h3[8];
#pragma unroll
        for (int m = 0; m < 8; ++m) {
            float s = b3[m];
#pragma unroll
            for (int j = 0; j < 10; ++j) s += h2[j] * W3[j * 8 + m];
            h3[m] = ftanh(s);
        }
        float h4[6];
#pragma unroll
        for (int m = 0; m < 6; ++m) {
            float s = b4[m];
#pragma unroll
            for (int j = 0; j < 8; ++j) s += h3[j] * W4[j * 6 + m];
            h4[m] = ftanh(s);
        }
        float h5[4];
#pragma unroll
        for (int m = 0; m < 4; ++m) {
            float s = b5[m];
#pragma unroll
            for (int j = 0; j < 6; ++j) s += h4[j] * W5[j * 4 + m];
            h5[m] = ftanh(s);
        }
        float o[10];
#pragma unroll
        for (int m = 0; m < 10; ++m) {
            float s = b6[m];
#pragma unroll
            for (int j = 0; j < 4; ++j) s += h5[j] * W6[j * 10 + m];
            o[m] = s;   // logits
        }

        const size_t H1o = 655360, H2o = 1441792, H3o = 2097152, H4o = 2621440, H5o = 3014656;
        float2* po  = (float2*)(out +       (size_t)row * 10);
        float4* ph1 = (float4*)(out + H1o + (size_t)row * 12);
        float2* ph2 = (float2*)(out + H2o + (size_t)row * 10);
        float4* ph3 = (float4*)(out + H3o + (size_t)row * 8);
        float2* ph4 = (float2*)(out + H4o + (size_t)row * 6);
        float4* ph5 = (float4*)(out + H5o + (size_t)row * 4);

        switch (s8) {
            case 0:
                po[0] = make_float2(o[0], o[1]);
                po[1] = make_float2(o[2], o[3]);
                po[2] = make_float2(o[4], o[5]);
                break;
            case 1:
                po[3] = make_float2(o[6], o[7]);
                po[4] = make_float2(o[8], o[9]);
                ph4[0] = make_float2(h4[0], h4[1]);
                break;
            case 2:
                ph1[0] = make_float4(h1[0], h1[1], h1[2], h1[3]);
                ph1[1] = make_float4(h1[4], h1[5], h1[6], h1[7]);
                ph4[1] = make_float2(h4[2], h4[3]);
                break;
            case 3:
                ph1[2] = make_float4(h1[8], h1[9], h1[10], h1[11]);
                ph2[0] = make_float2(h2[0], h2[1]);
                ph4[2] = make_float2(h4[4], h4[5]);
                break;
            case 4:
                ph2[1] = make_float2(h2[2], h2[3]);
                ph2[2] = make_float2(h2[4], h2[5]);
                break;
            case 5:
                ph2[3] = make_float2(h2[6], h2[7]);
                ph2[4] = make_float2(h2[8], h2[9]);
                break;
            case 6:
                ph3[0] = make_float4(h3[0], h3[1], h3[2], h3[3]);
                ph5[0] = make_float4(h5[0], h5[1], h5[2], h5[3]);
                break;
            default:
                ph3[1] = make_float4(h3[4], h3[5], h3[6], h3[7]);
                break;
        }
    }
}

extern "C" void kernel_launch(void* const* d_in, const int* in_sizes, int n_in,
                              void* d_out, int out_size, void* d_ws, size_t ws_size,
                              hipStream_t stream) {
    (void)in_sizes; (void)n_in; (void)d_ws; (void)ws_size; (void)out_size;
    mlp_fused14<<<2048, 512, 0, stream>>>(
        (const float*)d_in[0],
        (const float*)d_in[1],  (const float*)d_in[2],
        (const float*)d_in[3],  (const float*)d_in[4],
        (const float*)d_in[5],  (const float*)d_in[6],
        (const float*)d_in[7],  (const float*)d_in[8],
        (const float*)d_in[9],  (const float*)d_in[10],
        (const float*)d_in[11], (const float*)d_in[12],
        (float*)d_out);
}

// Round 14
// 73.912 us; speedup vs baseline: 2.4134x; 1.6198x over previous
//
#include <hip/hip_runtime.h>

// Fused 6-layer MLP, v15: linear-coalesced stage -> transposed bf16 xT in LDS,
// W1 bf16-pairs in LDS (broadcast ds_read_b128), v_dot2_f32_bf16 compute.
// Grid 2048 x 512 thr (8 waves; 69.1 KB LDS -> 2 blocks/CU). Block = 32 rows.
//   Stage: wave w stages rows {w,w+8,w+16,w+24}; lane l loads float2 (512B
//     contiguous per wave-instr), cvt_pk -> bf16 pair p=64c+l, writes
//     xT[r*393+p] (banks 9r+p: conflict-free).
//   Compute: wave w owns pairs [49w,49w+49). Per iter: 1 ds_read_b32 x
//     (banks r+p over r=0..31: conflict-free; lanes 32-63 broadcast-duplicate),
//     3 ds_read_b128 W (wave-uniform broadcast), 12 dot2.
//   Reduce: acc->regs, barrier, pt (aliases dead xT, stride 97) holds
//     [row][wave] partials, barrier, 256-thread epilogue: 8 slots/row,
//     shfl_xor(1,2,4), tiny layers redundant, stores split 8 ways.

__device__ __forceinline__ float ftanh(float v) {
    float e = __expf(2.0f * v);
    return 1.0f - 2.0f / (e + 1.0f);
}

__device__ __forceinline__ uint32_t cvtpk(float lo, float hi) {
    uint32_t d;
    asm("v_cvt_pk_bf16_f32 %0, %1, %2" : "=v"(d) : "v"(lo), "v"(hi));
    return d;
}

__device__ __forceinline__ float dot2(uint32_t a, uint32_t b, float c) {
    float d;
    asm("v_dot2_f32_bf16 %0, %1, %2, %3" : "=v"(d) : "v"(a), "v"(b), "v"(c));
    return d;
}

__global__ __launch_bounds__(512, 4)
void mlp_fused15(const float* __restrict__ x,
                 const float* __restrict__ W1, const float* __restrict__ b1,
                 const float* __restrict__ W2, const float* __restrict__ b2,
                 const float* __restrict__ W3, const float* __restrict__ b3,
                 const float* __restrict__ W4, const float* __restrict__ b4,
                 const float* __restrict__ W5, const float* __restrict__ b5,
                 const float* __restrict__ W6, const float* __restrict__ b6,
                 float* __restrict__ out)
{
    __shared__ uint32_t smem[12576 + 4704];   // xT[32][393] + lw[392*12] = 69,120 B
    uint32_t* const xT = smem;                 // [r][p] stride 393
    uint32_t* const lw = smem + 12576;         // [pair p][j] 12 u32 each
    float*    const pt = (float*)smem;         // aliases xT after barrier; [r][97]

    const int tid  = threadIdx.x;
    const int wave = __builtin_amdgcn_readfirstlane(tid >> 6);   // SGPR
    const int lane = tid & 63;
    const size_t row0 = (size_t)blockIdx.x << 5;    // 32 rows per block

    // ---- pack W1 -> LDS (bf16 k-pairs) ----
    for (int t = tid; t < 4704; t += 512) {
        int p = t / 12, j = t - p * 12;
        lw[t] = cvtpk(W1[p * 24 + j], W1[p * 24 + 12 + j]);
    }

    // ---- stage: 4 rows/wave, 512B-contiguous float2 bursts, transposed ----
#pragma unroll
    for (int i = 0; i < 4; ++i) {
        const int r = 8 * i + wave;
        const float* xp = x + (row0 + r) * 784;
#pragma unroll
        for (int c = 0; c < 6; ++c) {
            float2 v = *(const float2*)(xp + 128 * c + 2 * lane);
            xT[r * 393 + 64 * c + lane] = cvtpk(v.x, v.y);
        }
        if (lane < 8) {                 // pairs 384..391
            float2 v = *(const float2*)(xp + 768 + 2 * lane);
            xT[r * 393 + 384 + lane] = cvtpk(v.x, v.y);
        }
    }
    __syncthreads();

    // ---- compute: wave-uniform pair-slice, W broadcast from LDS ----
    const int r = lane & 31;
    float acc[12];
#pragma unroll
    for (int j = 0; j < 12; ++j) acc[j] = 0.f;

    {
        const int pbase = 49 * wave;
        const uint32_t* xrow = xT + r * 393 + pbase;
#pragma unroll 7
        for (int t = 0; t < 49; ++t) {
            uint32_t ux = xrow[t];
            const uint4* wb = (const uint4*)(lw + (pbase + t) * 12);
            uint4 A0 = wb[0], A1 = wb[1], A2 = wb[2];
            acc[0]  = dot2(ux, A0.x, acc[0]);
            acc[1]  = dot2(ux, A0.y, acc[1]);
            acc[2]  = dot2(ux, A0.z, acc[2]);
            acc[3]  = dot2(ux, A0.w, acc[3]);
            acc[4]  = dot2(ux, A1.x, acc[4]);
            acc[5]  = dot2(ux, A1.y, acc[5]);
            acc[6]  = dot2(ux, A1.z, acc[6]);
            acc[7]  = dot2(ux, A1.w, acc[7]);
            acc[8]  = dot2(ux, A2.x, acc[8]);
            acc[9]  = dot2(ux, A2.y, acc[9]);
            acc[10] = dot2(ux, A2.z, acc[10]);
            acc[11] = dot2(ux, A2.w, acc[11]);
        }
    }
    __syncthreads();                    // all xT reads done; region reusable

    if (lane < 32) {
#pragma unroll
        for (int j = 0; j < 12; ++j) pt[r * 97 + wave * 12 + j] = acc[j];
    }
    __syncthreads();

    // ---- epilogue: 256 threads, 8 slots per row ----
    if (tid < 256) {
        const int rr = tid >> 3;
        const int s8 = tid & 7;
        const int row = (int)row0 + rr;

        float h1[12];
#pragma unroll
        for (int j = 0; j < 12; ++j) {
            float z = pt[rr * 97 + s8 * 12 + j];
            z += __shfl_xor(z, 1);
            z += __shfl_xor(z, 2);
            z += __shfl_xor(z, 4);
            h1[j] = ftanh(z + b1[j]);
        }

        float h2[10];
#pragma unroll
        for (int m = 0; m < 10; ++m) {
            float s = b2[m];
#pragma unroll
            for (int j = 0; j < 12; ++j) s += h1[j] * W2[j * 10 + m];
            h2[m] = ftanh(s);
        }
        float h3[8];
#pragma unroll
        for (int m = 0; m < 8; ++m) {
            float s = b3[m];
#pragma unroll
            for (int j = 0; j < 10; ++j) s += h2[j] * W3[j * 8 + m];
            h3[m] = ftanh(s);
        }
        float h4[6];
#pragma unroll
        for (int m = 0; m < 6; ++m) {
            float s = b4[m];
#pragma unroll
            for (int j = 0; j < 8; ++j) s += h3[j] * W4[j * 6 + m];
            h4[m] = ftanh(s);
        }
        float h5[4];
#pragma unroll
        for (int m = 0; m < 4; ++m) {
            float s = b5[m];
#pragma unroll
            for (int j = 0; j < 6; ++j) s += h4[j] * W5[j * 4 + m];
            h5[m] = ftanh(s);
        }
        float o[10];
#pragma unroll
        for (int m = 0; m < 10; ++m) {
            float s = b6[m];
#pragma unroll
            for (int j = 0; j < 4; ++j) s += h5[j] * W6[j * 10 + m];
            o[m] = s;   // logits
        }

        const size_t H1o = 655360, H2o = 1441792, H3o = 2097152, H4o = 2621440, H5o = 3014656;
        float2* po  = (float2*)(out +       (size_t)row * 10);
        float4* ph1 = (float4*)(out + H1o + (size_t)row * 12);
        float2* ph2 = (float2*)(out + H2o + (size_t)row * 10);
        float4* ph3 = (float4*)(out + H3o + (size_t)row * 8);
        float2* ph4 = (float2*)(out + H4o + (size_t)row * 6);
        float4* ph5 = (float4*)(out + H5o + (size_t)row * 4);

        switch (s8) {
            case 0:
                po[0] = make_float2(o[0], o[1]);
                po[1] = make_float2(o[2], o[3]);
                po[2] = make_float2(o[4], o[5]);
                break;
            case 1:
                po[3] = make_float2(o[6], o[7]);
                po[4] = make_float2(o[8], o[9]);
                ph4[0] = make_float2(h4[0], h4[1]);
                break;
            case 2:
                ph1[0] = make_float4(h1[0], h1[1], h1[2], h1[3]);
                ph1[1] = make_float4(h1[4], h1[5], h1[6], h1[7]);
                ph4[1] = make_float2(h4[2], h4[3]);
                break;
            case 3:
                ph1[2] = make_float4(h1[8], h1[9], h1[10], h1[11]);
                ph2[0] = make_float2(h2[0], h2[1]);
                ph4[2] = make_float2(h4[4], h4[5]);
                break;
            case 4:
                ph2[1] = make_float2(h2[2], h2[3]);
                ph2[2] = make_float2(h2[4], h2[5]);
                break;
            case 5:
                ph2[3] = make_float2(h2[6], h2[7]);
                ph2[4] = make_float2(h2[8], h2[9]);
                break;
            case 6:
                ph3[0] = make_float4(h3[0], h3[1], h3[2], h3[3]);
                ph5[0] = make_float4(h5[0], h5[1], h5[2], h5[3]);
                break;
            default:
                ph3[1] = make_float4(h3[4], h3[5], h3[6], h3[7]);
                break;
        }
    }
}

extern "C" void kernel_launch(void* const* d_in, const int* in_sizes, int n_in,
                              void* d_out, int out_size, void* d_ws, size_t ws_size,
                              hipStream_t stream) {
    (void)in_sizes; (void)n_in; (void)d_ws; (void)ws_size; (void)out_size;
    mlp_fused15<<<2048, 512, 0, stream>>>(
        (const float*)d_in[0],
        (const float*)d_in[1],  (const float*)d_in[2],
        (const float*)d_in[3],  (const float*)d_in[4],
        (const float*)d_in[5],  (const float*)d_in[6],
        (const float*)d_in[7],  (const float*)d_in[8],
        (const float*)d_in[9],  (const float*)d_in[10],
        (const float*)d_in[11], (const float*)d_in[12],
        (float*)d_out);
}